// Round 7
// baseline (65.883 us; speedup 1.0000x reference)
//
#include <hip/hip_runtime.h>
#include <hip/hip_bf16.h>
#include <math.h>

#define H 192
#define W 192
#define HW (H*W)          // 36864
#define CIN 32
#define COUT 32
#define NB 4
#define NPOS (NB*HW)      // 147456
#define NBLK_F (NPOS/128) // 1152 blocks of 512 threads (8 waves x 16 pos)
#define NBLK0 (NPOS/256)  // 576 fallback blocks

typedef __attribute__((ext_vector_type(8))) short bf16x8;
typedef __attribute__((ext_vector_type(4))) float f32x4;
typedef __attribute__((ext_vector_type(2))) float f32x2;

__device__ __forceinline__ short f2bf(float f) {             // RNE (staging/transpose only)
    __hip_bfloat16 h = __float2bfloat16(f);
    short s; __builtin_memcpy(&s, &h, sizeof(s));
    return s;
}
__device__ __forceinline__ float bflo(unsigned u) { return __uint_as_float(u << 16); }
__device__ __forceinline__ float bfhi(unsigned u) { return __uint_as_float(u & 0xffff0000u); }
__device__ __forceinline__ unsigned getd(const uint4& v, int d) {
    return d == 0 ? v.x : d == 1 ? v.y : d == 2 ? v.z : v.w;
}

// bijective XCD-chunked swizzle (nblk % 8 == 0)
__device__ __forceinline__ int swz8(int bid, int nblk) {
    return (bid & 7) * (nblk >> 3) + (bid >> 3);
}

// ---------------------------------------------------------------------------
// Kernel A: NCHW fp32 -> NHWC bf16 transpose of x (RNE).
// ---------------------------------------------------------------------------
__global__ __launch_bounds__(256) void transpose_bf16_kernel(
    const float* __restrict__ x, unsigned short* __restrict__ xt)
{
    __shared__ float lds[32][65];
    const int tid = threadIdx.x;
    const int b   = blockIdx.x / (HW / 64);
    const int hw0 = (blockIdx.x % (HW / 64)) * 64;
    const float* xb = x + (size_t)b * CIN * HW;

    #pragma unroll
    for (int r = 0; r < 8; ++r) {
        const int c  = (tid >> 6) + 4 * r;
        const int hw = tid & 63;
        lds[c][hw] = xb[(size_t)c * HW + hw0 + hw];
    }
    __syncthreads();

    const int hw = tid >> 2;
    const int cg = tid & 3;
    uint4 o;
    #pragma unroll
    for (int d = 0; d < 4; ++d) {
        const unsigned lo = (unsigned short)f2bf(lds[cg * 8 + 2 * d][hw]);
        const unsigned hi = (unsigned short)f2bf(lds[cg * 8 + 2 * d + 1][hw]);
        const unsigned pk = lo | (hi << 16);
        if (d == 0) o.x = pk; else if (d == 1) o.y = pk; else if (d == 2) o.z = pk; else o.w = pk;
    }
    *reinterpret_cast<uint4*>(xt + ((size_t)(b * HW + hw0 + hw)) * 32 + cg * 8) = o;
}

// ---------------------------------------------------------------------------
// Kernel B: fused MFMA deformable conv (round-3 skeleton).
// 512 threads = 8 waves x 16 positions; both weight buffers staged ONCE with
// the round-3 element-wise loop (0 LDS bank conflicts: consecutive tids write
// consecutive shorts = 2 lanes/dword, free). om overlays b1s after phase 1.
// Phase-2 hot loop: packed-f32 interp + v_perm_b32 truncating bf16 pack.
// ---------------------------------------------------------------------------
__global__ __launch_bounds__(512, 4) void deform_mfma_kernel(
    const unsigned short* __restrict__ xt,
    const float* __restrict__ w_off, const float* __restrict__ b_off,
    const float* __restrict__ w_mod, const float* __restrict__ b_mod,
    const float* __restrict__ w_reg, float* __restrict__ out)
{
    __shared__ short b1s[9][2][64][8];   // phase1 weights; overlaid by om in phase 2
    __shared__ short b2s[9][2][64][8];   // phase2 weights
    __shared__ float bl[32];
    float* om = reinterpret_cast<float*>(&b1s[0][0][0][0]);   // 8*16*28*4 = 14336 B <= 18432 B

    const int tid = threadIdx.x;

    // ---- stage B-fragments (round-3 proven, conflict-free):
    // elem e of lane l = B[k = 8*(l>>4)+e][col = 16n+(l&15)]
    for (int i = tid; i < 9 * 2 * 64 * 8; i += 512) {
        const int e = i & 7, l = (i >> 3) & 63, n = (i >> 9) & 1, t = i >> 10;
        const int o = 16 * n + (l & 15);
        const int c = 8 * (l >> 4) + e;
        const int idx = c * 9 + t;
        const float v1 = (o < 18) ? w_off[o * 288 + idx]
                        : (o < 27 ? w_mod[(o - 18) * 288 + idx] : 0.0f);
        b1s[t][n][l][e] = f2bf(v1);
        b2s[t][n][l][e] = f2bf(w_reg[o * 288 + idx]);
    }
    if (tid < 32) bl[tid] = (tid < 18) ? b_off[tid] : (tid < 27 ? b_mod[tid - 18] : 0.0f);
    __syncthreads();

    const int lane = tid & 63;
    const int wv   = tid >> 6;
    const int prow = lane & 15;   // position (A row / C-D col role)
    const int kgrp = lane >> 4;   // channel group
    const int col  = prow;

    const int pos_wave = swz8(blockIdx.x, NBLK_F) * 128 + wv * 16;
    const int b    = pos_wave / HW;           // uniform per block (HW % 128 == 0)
    const int rem0 = pos_wave - b * HW;
    const int ho   = rem0 / W;
    const int wo0  = rem0 - ho * W;
    const int wo   = wo0 + prow;

    const char* xbc   = (const char*)(xt + (size_t)b * HW * 32);
    const int   kgoff = kgrp * 16;            // byte offset of this lane's 8 channels

    // ================= phase 1: offset/modulator conv (2-deep pipeline) ======
    f32x4 p1a = {0.f, 0.f, 0.f, 0.f}, p1b = {0.f, 0.f, 0.f, 0.f};
    uint4 xbuf[2]; unsigned okm[2];

    auto p1addr = [&](int t, int s) {
        const int ty = t / 3, tx = t - (t / 3) * 3;
        const int iy = ho + ty - 1, ix = wo + tx - 1;
        const bool ok = ((unsigned)iy < (unsigned)H) && ((unsigned)ix < (unsigned)W);
        const int cy = min(max(iy, 0), H - 1), cx = min(max(ix, 0), W - 1);
        okm[s]  = ok ? 0xffffffffu : 0u;
        xbuf[s] = *reinterpret_cast<const uint4*>(xbc + ((cy * W + cx) * 64 + kgoff));
    };

    p1addr(0, 0);
    #pragma unroll
    for (int t = 0; t < 9; ++t) {
        if (t < 8) p1addr(t + 1, (t + 1) & 1);
        const int s = t & 1;
        uint4 av;
        av.x = xbuf[s].x & okm[s]; av.y = xbuf[s].y & okm[s];
        av.z = xbuf[s].z & okm[s]; av.w = xbuf[s].w & okm[s];
        bf16x8 a; __builtin_memcpy(&a, &av, sizeof(a));
        const bf16x8 wb0 = *reinterpret_cast<const bf16x8*>(&b1s[t][0][lane][0]);
        const bf16x8 wb1 = *reinterpret_cast<const bf16x8*>(&b1s[t][1][lane][0]);
        p1a = __builtin_amdgcn_mfma_f32_16x16x32_bf16(a, wb0, p1a, 0, 0, 0);
        p1b = __builtin_amdgcn_mfma_f32_16x16x32_bf16(a, wb1, p1b, 0, 0, 0);
    }

    // ---- all waves done reading b1s -> safe to overlay om ----
    __syncthreads();

    {
        const float bias0 = bl[col], bias1 = bl[16 + col];
        float* omw = om + (wv * 16) * 28;
        #pragma unroll
        for (int r = 0; r < 4; ++r) {
            const int prc = kgrp * 4 + r;
            omw[prc * 28 + col] = p1a[r] + bias0;
            if (col < 11) {
                float v = p1b[r] + bias1;
                if (col >= 2) v = 2.0f / (1.0f + __expf(-v));   // ch18..26: 2*sigmoid
                omw[prc * 28 + 16 + col] = v;
            }
        }
    }
    // wave-local write->read of om[wv]: ordered by lgkmcnt within the wave
    f32x4 omr[7];
    #pragma unroll
    for (int q = 0; q < 7; ++q)
        omr[q] = *reinterpret_cast<const f32x4*>(om + (wv * 16 + prow) * 28 + q * 4);

    // ================= phase 2: deform sampling + contraction (pipelined) ====
    f32x4 p2a = {0.f, 0.f, 0.f, 0.f}, p2b = {0.f, 0.f, 0.f, 0.f};
    uint4 cb[2][4]; f32x4 wtb[2];

    auto p2tap = [&](int k, int s) {
        const int ky = k / 3, kx = k - (k / 3) * 3;
        const float oy = omr[(2 * k) >> 2][(2 * k) & 3];
        const float ox = omr[(2 * k + 1) >> 2][(2 * k + 1) & 3];
        const float m  = omr[(18 + k) >> 2][(18 + k) & 3];

        const float py  = oy + (float)(ho - 1 + ky);
        const float px  = ox + (float)(wo - 1 + kx);
        const float y0f = floorf(py);
        const float x0f = floorf(px);
        const float wy  = py - y0f;
        const float wx  = px - x0f;
        const int y0 = (int)y0f, x0 = (int)x0f;
        const int y1 = y0 + 1,  x1 = x0 + 1;

        const float vy0 = ((unsigned)y0 < (unsigned)H) ? 1.0f : 0.0f;
        const float vy1 = ((unsigned)y1 < (unsigned)H) ? 1.0f : 0.0f;
        const float vx0 = ((unsigned)x0 < (unsigned)W) ? 1.0f : 0.0f;
        const float vx1 = ((unsigned)x1 < (unsigned)W) ? 1.0f : 0.0f;

        f32x4 wt;
        wt[0] = (1.0f - wy) * (1.0f - wx) * vy0 * vx0 * m;
        wt[1] = (1.0f - wy) * wx          * vy0 * vx1 * m;
        wt[2] = wy * (1.0f - wx)          * vy1 * vx0 * m;
        wt[3] = wy * wx                   * vy1 * vx1 * m;
        wtb[s] = wt;

        const int cy0 = min(max(y0, 0), H - 1), cy1 = min(max(y1, 0), H - 1);
        const int cx0 = min(max(x0, 0), W - 1), cx1 = min(max(x1, 0), W - 1);
        const int r0 = cy0 * (W * 64), r1 = cy1 * (W * 64);
        const int c0 = cx0 * 64 + kgoff, c1 = cx1 * 64 + kgoff;
        cb[s][0] = *reinterpret_cast<const uint4*>(xbc + (r0 + c0));
        cb[s][1] = *reinterpret_cast<const uint4*>(xbc + (r0 + c1));
        cb[s][2] = *reinterpret_cast<const uint4*>(xbc + (r1 + c0));
        cb[s][3] = *reinterpret_cast<const uint4*>(xbc + (r1 + c1));
    };

    p2tap(0, 0);
    #pragma unroll
    for (int k = 0; k < 9; ++k) {
        if (k < 8) p2tap(k + 1, (k + 1) & 1);
        const int s = k & 1;
        const f32x4 w = wtb[s];
        const f32x2 w0 = {w[0], w[0]}, w1 = {w[1], w[1]};
        const f32x2 w2 = {w[2], w[2]}, w3 = {w[3], w[3]};
        const uint4 r00 = cb[s][0], r01 = cb[s][1], r10 = cb[s][2], r11 = cb[s][3];

        unsigned ap[4];
        #pragma unroll
        for (int d = 0; d < 4; ++d) {
            const unsigned u00 = getd(r00, d), u01 = getd(r01, d);
            const unsigned u10 = getd(r10, d), u11 = getd(r11, d);
            const f32x2 c00 = {bflo(u00), bfhi(u00)};
            const f32x2 c01 = {bflo(u01), bfhi(u01)};
            const f32x2 c10 = {bflo(u10), bfhi(u10)};
            const f32x2 c11 = {bflo(u11), bfhi(u11)};
            const f32x2 v = w0 * c00 + w1 * c01 + w2 * c10 + w3 * c11;  // v_pk_fma_f32
            // truncating pack {hi16(v1),hi16(v0)} -> one v_perm_b32
            ap[d] = __builtin_amdgcn_perm(__float_as_uint(v[1]), __float_as_uint(v[0]),
                                          0x07060302u);
        }
        bf16x8 a; __builtin_memcpy(&a, ap, sizeof(a));
        const bf16x8 wb0 = *reinterpret_cast<const bf16x8*>(&b2s[k][0][lane][0]);
        const bf16x8 wb1 = *reinterpret_cast<const bf16x8*>(&b2s[k][1][lane][0]);
        p2a = __builtin_amdgcn_mfma_f32_16x16x32_bf16(a, wb0, p2a, 0, 0, 0);
        p2b = __builtin_amdgcn_mfma_f32_16x16x32_bf16(a, wb1, p2b, 0, 0, 0);
    }

    // ---- epilogue: rows kgrp*4+r are consecutive hw -> two dwordx4 stores ----
    float* yb = out + (size_t)b * COUT * HW;
    const int hwb = rem0 + kgrp * 4;
    *reinterpret_cast<f32x4*>(yb + (size_t)col * HW + hwb)        = p2a;
    *reinterpret_cast<f32x4*>(yb + (size_t)(col + 16) * HW + hwb) = p2b;
}

// ---------------------------------------------------------------------------
// Fallback path (round-0 kernels, proven; used only if ws too small)
// ---------------------------------------------------------------------------
__global__ __launch_bounds__(256) void conv_offmod_kernel(
    const float* __restrict__ x,
    const float* __restrict__ w_off, const float* __restrict__ b_off,
    const float* __restrict__ w_mod, const float* __restrict__ b_mod,
    float* __restrict__ offs, float* __restrict__ modv)
{
    __shared__ float wl[288 * 28];
    __shared__ float bl[27];
    const int tid = threadIdx.x;

    for (int i = tid; i < 288 * 27; i += 256) {
        int j  = i / 27;
        int co = i - j * 27;
        wl[j * 28 + co] = (co < 18) ? w_off[co * 288 + j] : w_mod[(co - 18) * 288 + j];
    }
    for (int i = tid; i < 288; i += 256) wl[i * 28 + 27] = 0.0f;
    if (tid < 27) bl[tid] = (tid < 18) ? b_off[tid] : b_mod[tid - 18];
    __syncthreads();

    const int pos = blockIdx.x * 256 + tid;
    const int b   = pos / HW;
    const int rem = pos - b * HW;
    const int ho  = rem / W;
    const int wo  = rem - ho * W;

    float acc[28];
    #pragma unroll
    for (int q = 0; q < 27; ++q) acc[q] = bl[q];
    acc[27] = 0.0f;

    const float* xb = x + (size_t)b * (CIN * HW);
    for (int ci = 0; ci < CIN; ++ci) {
        const float* xc = xb + ci * HW;
        #pragma unroll
        for (int ky = 0; ky < 3; ++ky) {
            const int iy = ho + ky - 1;
            const bool yok = ((unsigned)iy < (unsigned)H);
            #pragma unroll
            for (int kx = 0; kx < 3; ++kx) {
                const int ix = wo + kx - 1;
                const float xv = (yok && ((unsigned)ix < (unsigned)W)) ? xc[iy * W + ix] : 0.0f;
                const float4* wr =
                    reinterpret_cast<const float4*>(&wl[(ci * 9 + ky * 3 + kx) * 28]);
                #pragma unroll
                for (int q = 0; q < 7; ++q) {
                    float4 wv = wr[q];
                    acc[4*q+0] += xv * wv.x;
                    acc[4*q+1] += xv * wv.y;
                    acc[4*q+2] += xv * wv.z;
                    acc[4*q+3] += xv * wv.w;
                }
            }
        }
    }

    float* ob = offs + (size_t)b * (18 * HW) + rem;
    #pragma unroll
    for (int co = 0; co < 18; ++co) ob[co * HW] = acc[co];
    float* mb = modv + (size_t)b * (9 * HW) + rem;
    #pragma unroll
    for (int j = 0; j < 9; ++j) mb[j * HW] = 2.0f / (1.0f + expf(-acc[18 + j]));
}

__global__ __launch_bounds__(256) void deform_kernel(
    const float* __restrict__ x,
    const float* __restrict__ offs, const float* __restrict__ modv,
    const float* __restrict__ w_reg, float* __restrict__ out)
{
    __shared__ float wl[288 * 32];
    const int tid = threadIdx.x;
    for (int i = tid; i < 288 * 32; i += 256) {
        int o  = i & 31;
        int ck = i >> 5;
        wl[i] = w_reg[o * 288 + ck];
    }
    __syncthreads();

    const int pos = blockIdx.x * 256 + tid;
    const int b   = pos / HW;
    const int rem = pos - b * HW;
    const int ho  = rem / W;
    const int wo  = rem - ho * W;

    const float* xb = x    + (size_t)b * (CIN * HW);
    const float* ob = offs + (size_t)b * (18 * HW) + rem;
    const float* mb = modv + (size_t)b * (9 * HW) + rem;

    float acc[32];
    #pragma unroll
    for (int o = 0; o < 32; ++o) acc[o] = 0.0f;

    for (int k = 0; k < 9; ++k) {
        const int ky = k / 3;
        const int kx = k - ky * 3;
        const float oy = ob[(2 * k) * HW];
        const float ox = ob[(2 * k + 1) * HW];
        const float m  = mb[k * HW];

        const float py  = oy + (float)(ho - 1 + ky);
        const float px  = ox + (float)(wo - 1 + kx);
        const float y0f = floorf(py);
        const float x0f = floorf(px);
        const float wy  = py - y0f;
        const float wx  = px - x0f;
        const int y0 = (int)y0f, x0 = (int)x0f;
        const int y1 = y0 + 1,  x1 = x0 + 1;

        const float vy0 = ((unsigned)y0 < (unsigned)H) ? 1.0f : 0.0f;
        const float vy1 = ((unsigned)y1 < (unsigned)H) ? 1.0f : 0.0f;
        const float vx0 = ((unsigned)x0 < (unsigned)W) ? 1.0f : 0.0f;
        const float vx1 = ((unsigned)x1 < (unsigned)W) ? 1.0f : 0.0f;

        const float w00 = (1.0f - wy) * (1.0f - wx) * vy0 * vx0 * m;
        const float w01 = (1.0f - wy) * wx          * vy0 * vx1 * m;
        const float w10 = wy * (1.0f - wx)          * vy1 * vx0 * m;
        const float w11 = wy * wx                   * vy1 * vx1 * m;

        const int cy0 = min(max(y0, 0), H - 1), cy1 = min(max(y1, 0), H - 1);
        const int cx0 = min(max(x0, 0), W - 1), cx1 = min(max(x1, 0), W - 1);
        const int l00 = cy0 * W + cx0, l01 = cy0 * W + cx1;
        const int l10 = cy1 * W + cx0, l11 = cy1 * W + cx1;

        for (int c = 0; c < CIN; ++c) {
            const float* xc = xb + c * HW;
            const float v = w00 * xc[l00] + w01 * xc[l01]
                          + w10 * xc[l10] + w11 * xc[l11];
            const float4* wr = reinterpret_cast<const float4*>(&wl[(c * 9 + k) * 32]);
            #pragma unroll
            for (int q = 0; q < 8; ++q) {
                float4 wv = wr[q];
                acc[4*q+0] += v * wv.x;
                acc[4*q+1] += v * wv.y;
                acc[4*q+2] += v * wv.z;
                acc[4*q+3] += v * wv.w;
            }
        }
    }

    float* yb = out + (size_t)b * (COUT * HW) + rem;
    #pragma unroll
    for (int o = 0; o < COUT; ++o) yb[o * HW] = acc[o];
}

// ---------------------------------------------------------------------------
extern "C" void kernel_launch(void* const* d_in, const int* in_sizes, int n_in,
                              void* d_out, int out_size, void* d_ws, size_t ws_size,
                              hipStream_t stream) {
    const float* x     = (const float*)d_in[0];
    const float* w_off = (const float*)d_in[1];
    const float* b_off = (const float*)d_in[2];
    const float* w_mod = (const float*)d_in[3];
    const float* b_mod = (const float*)d_in[4];
    const float* w_reg = (const float*)d_in[5];
    float* out = (float*)d_out;

    const size_t need_fast = (size_t)NPOS * 32 * sizeof(unsigned short);  // 9.4 MB bf16 NHWC
    if (ws_size >= need_fast) {
        unsigned short* xt = (unsigned short*)d_ws;
        transpose_bf16_kernel<<<dim3(NB * (HW / 64)), dim3(256), 0, stream>>>(x, xt);
        deform_mfma_kernel<<<dim3(NBLK_F), dim3(512), 0, stream>>>(
            xt, w_off, b_off, w_mod, b_mod, w_reg, out);
    } else {
        float* offs = (float*)d_ws;
        float* modv = offs + (size_t)NB * 18 * HW;
        dim3 grid(NBLK0), blk(256);
        conv_offmod_kernel<<<grid, blk, 0, stream>>>(x, w_off, b_off, w_mod, b_mod, offs, modv);
        deform_kernel<<<grid, blk, 0, stream>>>(x, offs, modv, w_reg, out);
    }
}

// Round 8
// 50.651 us; speedup vs baseline: 1.3007x; 1.3007x over previous
//
#include <hip/hip_runtime.h>
#include <hip/hip_bf16.h>
#include <math.h>

#define H 192
#define W 192
#define HW (H*W)          // 36864
#define CIN 32
#define COUT 32
#define NB 4
#define NPOS (NB*HW)      // 147456
#define NBLK_F (NPOS/128) // 1152 blocks of 512 threads (8 waves x 16 pos)
#define NBLK0 (NPOS/256)  // 576 fallback blocks
#define NBXT (NB*(HW/64)) // 2304 transpose blocks
#define NWPB 8            // weight-prep blocks appended to transpose grid
#define WFRAG_N 9216      // shorts per fragment table

typedef __attribute__((ext_vector_type(8))) short bf16x8;
typedef __attribute__((ext_vector_type(4))) float f32x4;
typedef __attribute__((ext_vector_type(2))) float f32x2;

__device__ __forceinline__ short f2bf(float f) {             // RNE (prep/transpose only)
    __hip_bfloat16 h = __float2bfloat16(f);
    short s; __builtin_memcpy(&s, &h, sizeof(s));
    return s;
}
__device__ __forceinline__ float bflo(unsigned u) { return __uint_as_float(u << 16); }
__device__ __forceinline__ float bfhi(unsigned u) { return __uint_as_float(u & 0xffff0000u); }
__device__ __forceinline__ unsigned getd(const uint4& v, int d) {
    return d == 0 ? v.x : d == 1 ? v.y : d == 2 ? v.z : v.w;
}

// bijective XCD-chunked swizzle (nblk % 8 == 0)
__device__ __forceinline__ int swz8(int bid, int nblk) {
    return (bid & 7) * (nblk >> 3) + (bid >> 3);
}

// ---------------------------------------------------------------------------
// Kernel A: NCHW fp32 -> NHWC bf16 transpose of x (blocks 0..NBXT-1) plus
// weight-fragment precompute into d_ws (blocks NBXT..NBXT+NWPB-1).
// Fragment layout (shorts): wf[(t*2+n)*512 + l*8 + e] = bf16(W[o][c][t]),
// o = 16n+(l&15), c = 8*(l>>4)+e.  wf1 = conv (w_off||w_mod), wf2 = w_reg.
// ---------------------------------------------------------------------------
__global__ __launch_bounds__(256) void transpose_bf16_kernel(
    const float* __restrict__ x, unsigned short* __restrict__ xt,
    const float* __restrict__ w_off, const float* __restrict__ w_mod,
    const float* __restrict__ w_reg, unsigned short* __restrict__ wf)
{
    const int tid = threadIdx.x;
    const int bid = blockIdx.x;

    if (bid >= NBXT) {                        // ---- weight-fragment prep ----
        const int base = (bid - NBXT) * (WFRAG_N / NWPB);
        for (int i = base + tid; i < base + WFRAG_N / NWPB; i += 256) {
            const int e = i & 7, l = (i >> 3) & 63, n = (i >> 9) & 1, t = i >> 10;
            const int o = 16 * n + (l & 15);
            const int c = 8 * (l >> 4) + e;
            const int idx = c * 9 + t;
            const float v1 = (o < 18) ? w_off[o * 288 + idx]
                            : (o < 27 ? w_mod[(o - 18) * 288 + idx] : 0.0f);
            wf[i]           = (unsigned short)f2bf(v1);
            wf[WFRAG_N + i] = (unsigned short)f2bf(w_reg[o * 288 + idx]);
        }
        return;
    }

    __shared__ float lds[32][65];
    const int b   = bid / (HW / 64);
    const int hw0 = (bid % (HW / 64)) * 64;
    const float* xb = x + (size_t)b * CIN * HW;

    #pragma unroll
    for (int r = 0; r < 8; ++r) {
        const int c  = (tid >> 6) + 4 * r;
        const int hw = tid & 63;
        lds[c][hw] = xb[(size_t)c * HW + hw0 + hw];
    }
    __syncthreads();

    const int hw = tid >> 2;
    const int cg = tid & 3;
    uint4 o;
    #pragma unroll
    for (int d = 0; d < 4; ++d) {
        const unsigned lo = (unsigned short)f2bf(lds[cg * 8 + 2 * d][hw]);
        const unsigned hi = (unsigned short)f2bf(lds[cg * 8 + 2 * d + 1][hw]);
        const unsigned pk = lo | (hi << 16);
        if (d == 0) o.x = pk; else if (d == 1) o.y = pk; else if (d == 2) o.z = pk; else o.w = pk;
    }
    *reinterpret_cast<uint4*>(xt + ((size_t)(b * HW + hw0 + hw)) * 32 + cg * 8) = o;
}

// ---------------------------------------------------------------------------
// Kernel B: fused MFMA deformable conv. Staging is now a flat 36864-B copy
// (coalesced dwordx4 global loads -> contiguous ds_write_b128, 0 conflicts,
// 0 index math). om overlays wsh[0] after phase 1. Phase-2 hot loop:
// packed-f32 interp + v_perm_b32 truncating bf16 pack.
// ---------------------------------------------------------------------------
__global__ __launch_bounds__(512, 4) void deform_mfma_kernel(
    const unsigned short* __restrict__ xt, const unsigned short* __restrict__ wf,
    const float* __restrict__ b_off, const float* __restrict__ b_mod,
    float* __restrict__ out)
{
    __shared__ __align__(16) short wsh[2][9][2][64][8];   // [0]=conv, [1]=deform; 36864 B
    __shared__ float bl[32];
    float* om = reinterpret_cast<float*>(&wsh[0][0][0][0][0]);  // 14336 B <= 18432 B

    const int tid = threadIdx.x;

    // ---- staging: flat copy of both fragment tables ----
    {
        const uint4* src = reinterpret_cast<const uint4*>(wf);
        uint4* dst = reinterpret_cast<uint4*>(&wsh[0][0][0][0][0]);
        #pragma unroll
        for (int r = 0; r < 5; ++r) {                 // ceil(2304/512)=5, last partial
            const int i = tid + r * 512;
            if (i < 2304) dst[i] = src[i];
        }
    }
    if (tid < 32) bl[tid] = (tid < 18) ? b_off[tid] : (tid < 27 ? b_mod[tid - 18] : 0.0f);
    __syncthreads();

    const int lane = tid & 63;
    const int wv   = tid >> 6;
    const int prow = lane & 15;   // position (A row / C-D col role)
    const int kgrp = lane >> 4;   // channel group
    const int col  = prow;

    const int pos_wave = swz8(blockIdx.x, NBLK_F) * 128 + wv * 16;
    const int b    = pos_wave / HW;           // uniform per block (HW % 128 == 0)
    const int rem0 = pos_wave - b * HW;
    const int ho   = rem0 / W;
    const int wo0  = rem0 - ho * W;
    const int wo   = wo0 + prow;

    const char* xbc   = (const char*)(xt + (size_t)b * HW * 32);
    const int   kgoff = kgrp * 16;            // byte offset of this lane's 8 channels

    // ================= phase 1: offset/modulator conv (2-deep pipeline) ======
    f32x4 p1a = {0.f, 0.f, 0.f, 0.f}, p1b = {0.f, 0.f, 0.f, 0.f};
    uint4 xbuf[2]; unsigned okm[2];

    auto p1addr = [&](int t, int s) {
        const int ty = t / 3, tx = t - (t / 3) * 3;
        const int iy = ho + ty - 1, ix = wo + tx - 1;
        const bool ok = ((unsigned)iy < (unsigned)H) && ((unsigned)ix < (unsigned)W);
        const int cy = min(max(iy, 0), H - 1), cx = min(max(ix, 0), W - 1);
        okm[s]  = ok ? 0xffffffffu : 0u;
        xbuf[s] = *reinterpret_cast<const uint4*>(xbc + ((cy * W + cx) * 64 + kgoff));
    };

    p1addr(0, 0);
    #pragma unroll
    for (int t = 0; t < 9; ++t) {
        if (t < 8) p1addr(t + 1, (t + 1) & 1);
        const int s = t & 1;
        uint4 av;
        av.x = xbuf[s].x & okm[s]; av.y = xbuf[s].y & okm[s];
        av.z = xbuf[s].z & okm[s]; av.w = xbuf[s].w & okm[s];
        bf16x8 a; __builtin_memcpy(&a, &av, sizeof(a));
        const bf16x8 wb0 = *reinterpret_cast<const bf16x8*>(&wsh[0][t][0][lane][0]);
        const bf16x8 wb1 = *reinterpret_cast<const bf16x8*>(&wsh[0][t][1][lane][0]);
        p1a = __builtin_amdgcn_mfma_f32_16x16x32_bf16(a, wb0, p1a, 0, 0, 0);
        p1b = __builtin_amdgcn_mfma_f32_16x16x32_bf16(a, wb1, p1b, 0, 0, 0);
    }

    // ---- all waves done reading wsh[0] -> safe to overlay om ----
    __syncthreads();

    {
        const float bias0 = bl[col], bias1 = bl[16 + col];
        float* omw = om + (wv * 16) * 28;
        #pragma unroll
        for (int r = 0; r < 4; ++r) {
            const int prc = kgrp * 4 + r;
            omw[prc * 28 + col] = p1a[r] + bias0;
            if (col < 11) {
                float v = p1b[r] + bias1;
                if (col >= 2) v = 2.0f / (1.0f + __expf(-v));   // ch18..26: 2*sigmoid
                omw[prc * 28 + 16 + col] = v;
            }
        }
    }
    // wave-local write->read of om[wv]: ordered by lgkmcnt within the wave
    f32x4 omr[7];
    #pragma unroll
    for (int q = 0; q < 7; ++q)
        omr[q] = *reinterpret_cast<const f32x4*>(om + (wv * 16 + prow) * 28 + q * 4);

    // ================= phase 2: deform sampling + contraction (pipelined) ====
    f32x4 p2a = {0.f, 0.f, 0.f, 0.f}, p2b = {0.f, 0.f, 0.f, 0.f};
    uint4 cb[2][4]; f32x4 wtb[2];

    auto p2tap = [&](int k, int s) {
        const int ky = k / 3, kx = k - (k / 3) * 3;
        const float oy = omr[(2 * k) >> 2][(2 * k) & 3];
        const float ox = omr[(2 * k + 1) >> 2][(2 * k + 1) & 3];
        const float m  = omr[(18 + k) >> 2][(18 + k) & 3];

        const float py  = oy + (float)(ho - 1 + ky);
        const float px  = ox + (float)(wo - 1 + kx);
        const float y0f = floorf(py);
        const float x0f = floorf(px);
        const float wy  = py - y0f;
        const float wx  = px - x0f;
        const int y0 = (int)y0f, x0 = (int)x0f;
        const int y1 = y0 + 1,  x1 = x0 + 1;

        const float vy0 = ((unsigned)y0 < (unsigned)H) ? 1.0f : 0.0f;
        const float vy1 = ((unsigned)y1 < (unsigned)H) ? 1.0f : 0.0f;
        const float vx0 = ((unsigned)x0 < (unsigned)W) ? 1.0f : 0.0f;
        const float vx1 = ((unsigned)x1 < (unsigned)W) ? 1.0f : 0.0f;

        f32x4 wt;
        wt[0] = (1.0f - wy) * (1.0f - wx) * vy0 * vx0 * m;
        wt[1] = (1.0f - wy) * wx          * vy0 * vx1 * m;
        wt[2] = wy * (1.0f - wx)          * vy1 * vx0 * m;
        wt[3] = wy * wx                   * vy1 * vx1 * m;
        wtb[s] = wt;

        const int cy0 = min(max(y0, 0), H - 1), cy1 = min(max(y1, 0), H - 1);
        const int cx0 = min(max(x0, 0), W - 1), cx1 = min(max(x1, 0), W - 1);
        const int r0 = cy0 * (W * 64), r1 = cy1 * (W * 64);
        const int c0 = cx0 * 64 + kgoff, c1 = cx1 * 64 + kgoff;
        cb[s][0] = *reinterpret_cast<const uint4*>(xbc + (r0 + c0));
        cb[s][1] = *reinterpret_cast<const uint4*>(xbc + (r0 + c1));
        cb[s][2] = *reinterpret_cast<const uint4*>(xbc + (r1 + c0));
        cb[s][3] = *reinterpret_cast<const uint4*>(xbc + (r1 + c1));
    };

    p2tap(0, 0);
    #pragma unroll
    for (int k = 0; k < 9; ++k) {
        if (k < 8) p2tap(k + 1, (k + 1) & 1);
        const int s = k & 1;
        const f32x4 w = wtb[s];
        const f32x2 w0 = {w[0], w[0]}, w1 = {w[1], w[1]};
        const f32x2 w2 = {w[2], w[2]}, w3 = {w[3], w[3]};
        const uint4 r00 = cb[s][0], r01 = cb[s][1], r10 = cb[s][2], r11 = cb[s][3];

        unsigned ap[4];
        #pragma unroll
        for (int d = 0; d < 4; ++d) {
            const unsigned u00 = getd(r00, d), u01 = getd(r01, d);
            const unsigned u10 = getd(r10, d), u11 = getd(r11, d);
            const f32x2 c00 = {bflo(u00), bfhi(u00)};
            const f32x2 c01 = {bflo(u01), bfhi(u01)};
            const f32x2 c10 = {bflo(u10), bfhi(u10)};
            const f32x2 c11 = {bflo(u11), bfhi(u11)};
            const f32x2 v = w0 * c00 + w1 * c01 + w2 * c10 + w3 * c11;  // v_pk_fma_f32
            // truncating pack {hi16(v1),hi16(v0)} -> one v_perm_b32
            ap[d] = __builtin_amdgcn_perm(__float_as_uint(v[1]), __float_as_uint(v[0]),
                                          0x07060302u);
        }
        bf16x8 a; __builtin_memcpy(&a, ap, sizeof(a));
        const bf16x8 wb0 = *reinterpret_cast<const bf16x8*>(&wsh[1][k][0][lane][0]);
        const bf16x8 wb1 = *reinterpret_cast<const bf16x8*>(&wsh[1][k][1][lane][0]);
        p2a = __builtin_amdgcn_mfma_f32_16x16x32_bf16(a, wb0, p2a, 0, 0, 0);
        p2b = __builtin_amdgcn_mfma_f32_16x16x32_bf16(a, wb1, p2b, 0, 0, 0);
    }

    // ---- epilogue: rows kgrp*4+r are consecutive hw -> two dwordx4 stores ----
    float* yb = out + (size_t)b * COUT * HW;
    const int hwb = rem0 + kgrp * 4;
    *reinterpret_cast<f32x4*>(yb + (size_t)col * HW + hwb)        = p2a;
    *reinterpret_cast<f32x4*>(yb + (size_t)(col + 16) * HW + hwb) = p2b;
}

// ---------------------------------------------------------------------------
// Fallback path (round-0 kernels, proven; used only if ws too small)
// ---------------------------------------------------------------------------
__global__ __launch_bounds__(256) void conv_offmod_kernel(
    const float* __restrict__ x,
    const float* __restrict__ w_off, const float* __restrict__ b_off,
    const float* __restrict__ w_mod, const float* __restrict__ b_mod,
    float* __restrict__ offs, float* __restrict__ modv)
{
    __shared__ float wl[288 * 28];
    __shared__ float bl[27];
    const int tid = threadIdx.x;

    for (int i = tid; i < 288 * 27; i += 256) {
        int j  = i / 27;
        int co = i - j * 27;
        wl[j * 28 + co] = (co < 18) ? w_off[co * 288 + j] : w_mod[(co - 18) * 288 + j];
    }
    for (int i = tid; i < 288; i += 256) wl[i * 28 + 27] = 0.0f;
    if (tid < 27) bl[tid] = (tid < 18) ? b_off[tid] : b_mod[tid - 18];
    __syncthreads();

    const int pos = blockIdx.x * 256 + tid;
    const int b   = pos / HW;
    const int rem = pos - b * HW;
    const int ho  = rem / W;
    const int wo  = rem - ho * W;

    float acc[28];
    #pragma unroll
    for (int q = 0; q < 27; ++q) acc[q] = bl[q];
    acc[27] = 0.0f;

    const float* xb = x + (size_t)b * (CIN * HW);
    for (int ci = 0; ci < CIN; ++ci) {
        const float* xc = xb + ci * HW;
        #pragma unroll
        for (int ky = 0; ky < 3; ++ky) {
            const int iy = ho + ky - 1;
            const bool yok = ((unsigned)iy < (unsigned)H);
            #pragma unroll
            for (int kx = 0; kx < 3; ++kx) {
                const int ix = wo + kx - 1;
                const float xv = (yok && ((unsigned)ix < (unsigned)W)) ? xc[iy * W + ix] : 0.0f;
                const float4* wr =
                    reinterpret_cast<const float4*>(&wl[(ci * 9 + ky * 3 + kx) * 28]);
                #pragma unroll
                for (int q = 0; q < 7; ++q) {
                    float4 wv = wr[q];
                    acc[4*q+0] += xv * wv.x;
                    acc[4*q+1] += xv * wv.y;
                    acc[4*q+2] += xv * wv.z;
                    acc[4*q+3] += xv * wv.w;
                }
            }
        }
    }

    float* ob = offs + (size_t)b * (18 * HW) + rem;
    #pragma unroll
    for (int co = 0; co < 18; ++co) ob[co * HW] = acc[co];
    float* mb = modv + (size_t)b * (9 * HW) + rem;
    #pragma unroll
    for (int j = 0; j < 9; ++j) mb[j * HW] = 2.0f / (1.0f + expf(-acc[18 + j]));
}

__global__ __launch_bounds__(256) void deform_kernel(
    const float* __restrict__ x,
    const float* __restrict__ offs, const float* __restrict__ modv,
    const float* __restrict__ w_reg, float* __restrict__ out)
{
    __shared__ float wl[288 * 32];
    const int tid = threadIdx.x;
    for (int i = tid; i < 288 * 32; i += 256) {
        int o  = i & 31;
        int ck = i >> 5;
        wl[i] = w_reg[o * 288 + ck];
    }
    __syncthreads();

    const int pos = blockIdx.x * 256 + tid;
    const int b   = pos / HW;
    const int rem = pos - b * HW;
    const int ho  = rem / W;
    const int wo  = rem - ho * W;

    const float* xb = x    + (size_t)b * (CIN * HW);
    const float* ob = offs + (size_t)b * (18 * HW) + rem;
    const float* mb = modv + (size_t)b * (9 * HW) + rem;

    float acc[32];
    #pragma unroll
    for (int o = 0; o < 32; ++o) acc[o] = 0.0f;

    for (int k = 0; k < 9; ++k) {
        const int ky = k / 3;
        const int kx = k - ky * 3;
        const float oy = ob[(2 * k) * HW];
        const float ox = ob[(2 * k + 1) * HW];
        const float m  = mb[k * HW];

        const float py  = oy + (float)(ho - 1 + ky);
        const float px  = ox + (float)(wo - 1 + kx);
        const float y0f = floorf(py);
        const float x0f = floorf(px);
        const float wy  = py - y0f;
        const float wx  = px - x0f;
        const int y0 = (int)y0f, x0 = (int)x0f;
        const int y1 = y0 + 1,  x1 = x0 + 1;

        const float vy0 = ((unsigned)y0 < (unsigned)H) ? 1.0f : 0.0f;
        const float vy1 = ((unsigned)y1 < (unsigned)H) ? 1.0f : 0.0f;
        const float vx0 = ((unsigned)x0 < (unsigned)W) ? 1.0f : 0.0f;
        const float vx1 = ((unsigned)x1 < (unsigned)W) ? 1.0f : 0.0f;

        const float w00 = (1.0f - wy) * (1.0f - wx) * vy0 * vx0 * m;
        const float w01 = (1.0f - wy) * wx          * vy0 * vx1 * m;
        const float w10 = wy * (1.0f - wx)          * vy1 * vx0 * m;
        const float w11 = wy * wx                   * vy1 * vx1 * m;

        const int cy0 = min(max(y0, 0), H - 1), cy1 = min(max(y1, 0), H - 1);
        const int cx0 = min(max(x0, 0), W - 1), cx1 = min(max(x1, 0), W - 1);
        const int l00 = cy0 * W + cx0, l01 = cy0 * W + cx1;
        const int l10 = cy1 * W + cx0, l11 = cy1 * W + cx1;

        for (int c = 0; c < CIN; ++c) {
            const float* xc = xb + c * HW;
            const float v = w00 * xc[l00] + w01 * xc[l01]
                          + w10 * xc[l10] + w11 * xc[l11];
            const float4* wr = reinterpret_cast<const float4*>(&wl[(c * 9 + k) * 32]);
            #pragma unroll
            for (int q = 0; q < 8; ++q) {
                float4 wv = wr[q];
                acc[4*q+0] += v * wv.x;
                acc[4*q+1] += v * wv.y;
                acc[4*q+2] += v * wv.z;
                acc[4*q+3] += v * wv.w;
            }
        }
    }

    float* yb = out + (size_t)b * (COUT * HW) + rem;
    #pragma unroll
    for (int o = 0; o < COUT; ++o) yb[o * HW] = acc[o];
}

// ---------------------------------------------------------------------------
extern "C" void kernel_launch(void* const* d_in, const int* in_sizes, int n_in,
                              void* d_out, int out_size, void* d_ws, size_t ws_size,
                              hipStream_t stream) {
    const float* x     = (const float*)d_in[0];
    const float* w_off = (const float*)d_in[1];
    const float* b_off = (const float*)d_in[2];
    const float* w_mod = (const float*)d_in[3];
    const float* b_mod = (const float*)d_in[4];
    const float* w_reg = (const float*)d_in[5];
    float* out = (float*)d_out;

    const size_t xt_bytes  = (size_t)NPOS * 32 * sizeof(unsigned short);  // 9.44 MB
    const size_t need_fast = xt_bytes + 2 * WFRAG_N * sizeof(unsigned short);
    if (ws_size >= need_fast) {
        unsigned short* xt = (unsigned short*)d_ws;
        unsigned short* wf = xt + (size_t)NPOS * 32;
        transpose_bf16_kernel<<<dim3(NBXT + NWPB), dim3(256), 0, stream>>>(
            x, xt, w_off, w_mod, w_reg, wf);
        deform_mfma_kernel<<<dim3(NBLK_F), dim3(512), 0, stream>>>(
            xt, wf, b_off, b_mod, out);
    } else {
        float* offs = (float*)d_ws;
        float* modv = offs + (size_t)NB * 18 * HW;
        dim3 grid(NBLK0), blk(256);
        conv_offmod_kernel<<<grid, blk, 0, stream>>>(x, w_off, b_off, w_mod, b_mod, offs, modv);
        deform_kernel<<<grid, blk, 0, stream>>>(x, offs, modv, w_reg, out);
    }
}